// Round 1
// baseline (1576.714 us; speedup 1.0000x reference)
//
#include <hip/hip_runtime.h>

#define N_USERS 200000
#define N_ITEMS 100000
#define N_NODES 300000
#define DIM 64
#define N_INTER 1000000

// ---------------- degree ----------------
__global__ void degree_kernel(const int* __restrict__ uid, const int* __restrict__ iid,
                              unsigned int* __restrict__ deg) {
    int k = blockIdx.x * blockDim.x + threadIdx.x;
    if (k < N_INTER) {
        atomicAdd(&deg[uid[k]], 1u);
        atomicAdd(&deg[N_USERS + iid[k]], 1u);
    }
}

// ---------------- d^{-1/2} ----------------
__global__ void dinv_kernel(const unsigned int* __restrict__ deg, float* __restrict__ dinv) {
    int n = blockIdx.x * blockDim.x + threadIdx.x;
    if (n < N_NODES) {
        unsigned int d = deg[n];
        dinv[n] = (d > 0) ? rsqrtf((float)d) : 0.0f;
    }
}

// ---------------- init emb_cur and acc(=d_out) ----------------
__global__ void init_kernel(const float4* __restrict__ ue, const float4* __restrict__ ie,
                            float4* __restrict__ cur, float4* __restrict__ acc) {
    int idx = blockIdx.x * blockDim.x + threadIdx.x;  // over N_NODES*16 float4s
    if (idx < N_NODES * 16) {
        float4 v = (idx < N_USERS * 16) ? ue[idx] : ie[idx - N_USERS * 16];
        cur[idx] = v;
        acc[idx] = v;
    }
}

// ---------------- SpMM scatter: one wave (64 lanes) per interaction ----------------
// lane d handles embedding dim d; both edge directions done by the same wave.
__global__ void scatter_kernel(const int* __restrict__ uid, const int* __restrict__ iid,
                               const float* __restrict__ dinv,
                               const float* __restrict__ cur, float* __restrict__ nxt) {
    int gid = blockIdx.x * blockDim.x + threadIdx.x;
    int k = gid >> 6;      // interaction index
    int lane = gid & 63;   // embedding dim
    if (k < N_INTER) {
        int u = uid[k];
        int it = N_USERS + iid[k];
        float w = dinv[u] * dinv[it];
        float a = cur[u * DIM + lane];   // user row
        float b = cur[it * DIM + lane];  // item row
        atomicAdd(&nxt[it * DIM + lane], w * a);  // user -> item
        atomicAdd(&nxt[u * DIM + lane], w * b);   // item -> user
    }
}

// ---------------- acc = (acc + nxt) * scale ----------------
__global__ void accum_kernel(const float4* __restrict__ nxt, float4* __restrict__ acc, float scale) {
    int idx = blockIdx.x * blockDim.x + threadIdx.x;
    if (idx < N_NODES * 16) {
        float4 a = acc[idx];
        float4 n = nxt[idx];
        a.x = (a.x + n.x) * scale;
        a.y = (a.y + n.y) * scale;
        a.z = (a.z + n.z) * scale;
        a.w = (a.w + n.w) * scale;
        acc[idx] = a;
    }
}

extern "C" void kernel_launch(void* const* d_in, const int* in_sizes, int n_in,
                              void* d_out, int out_size, void* d_ws, size_t ws_size,
                              hipStream_t stream) {
    const float* ue = (const float*)d_in[0];  // [N_USERS, 64]
    const float* ie = (const float*)d_in[1];  // [N_ITEMS, 64]
    const int* uid = (const int*)d_in[2];     // [N_INTER]
    const int* iid = (const int*)d_in[3];     // [N_INTER]
    float* out = (float*)d_out;               // [N_NODES, 64] (users then items)

    char* ws = (char*)d_ws;
    unsigned int* deg = (unsigned int*)ws;                       // N_NODES u32
    float* dinv = (float*)(ws + (size_t)N_NODES * 4);            // N_NODES f32
    size_t off = ((size_t)N_NODES * 8 + 255) & ~(size_t)255;
    float* buf0 = (float*)(ws + off);                            // N_NODES*64 f32
    float* buf1 = (float*)(ws + off + (size_t)N_NODES * DIM * 4);

    // degrees
    hipMemsetAsync(deg, 0, (size_t)N_NODES * 4, stream);
    degree_kernel<<<(N_INTER + 255) / 256, 256, 0, stream>>>(uid, iid, deg);
    dinv_kernel<<<(N_NODES + 255) / 256, 256, 0, stream>>>(deg, dinv);

    // init
    init_kernel<<<(N_NODES * 16 + 255) / 256, 256, 0, stream>>>(
        (const float4*)ue, (const float4*)ie, (float4*)buf0, (float4*)out);

    // 3 propagation layers
    float* cur = buf0;
    float* nxt = buf1;
    for (int l = 0; l < 3; ++l) {
        hipMemsetAsync(nxt, 0, (size_t)N_NODES * DIM * 4, stream);
        scatter_kernel<<<(N_INTER * 64) / 256, 256, 0, stream>>>(uid, iid, dinv, cur, nxt);
        accum_kernel<<<(N_NODES * 16 + 255) / 256, 256, 0, stream>>>(
            (const float4*)nxt, (float4*)out, (l == 2) ? 0.25f : 1.0f);
        float* t = cur; cur = nxt; nxt = t;
    }
}

// Round 2
// 946.803 us; speedup vs baseline: 1.6653x; 1.6653x over previous
//
#include <hip/hip_runtime.h>

#define N_USERS 200000
#define N_ITEMS 100000
#define N_NODES 300000
#define DIM 64
#define N_INTER 1000000
#define NB_SCAN ((N_NODES + 255) / 256)   // 1172 blocks

// ---------------- degree ----------------
__global__ void degree_kernel(const int* __restrict__ uid, const int* __restrict__ iid,
                              unsigned int* __restrict__ deg) {
    int k = blockIdx.x * blockDim.x + threadIdx.x;
    if (k < N_INTER) {
        atomicAdd(&deg[uid[k]], 1u);
        atomicAdd(&deg[N_USERS + iid[k]], 1u);
    }
}

// ---------------- d^{-1/2} ----------------
__global__ void dinv_kernel(const unsigned int* __restrict__ deg, float* __restrict__ dinv) {
    int n = blockIdx.x * blockDim.x + threadIdx.x;
    if (n < N_NODES) {
        unsigned int d = deg[n];
        dinv[n] = (d > 0) ? rsqrtf((float)d) : 0.0f;
    }
}

// ---------------- scan step 1: per-block sums ----------------
__global__ void scan1_kernel(const unsigned int* __restrict__ deg, unsigned int* __restrict__ partial) {
    __shared__ unsigned int sh[256];
    int t = threadIdx.x;
    int i = blockIdx.x * 256 + t;
    sh[t] = (i < N_NODES) ? deg[i] : 0u;
    __syncthreads();
    for (int o = 128; o > 0; o >>= 1) {
        if (t < o) sh[t] += sh[t + o];
        __syncthreads();
    }
    if (t == 0) partial[blockIdx.x] = sh[0];
}

// ---------------- scan step 2: exclusive scan of partials (single block) ----------------
__global__ void scan2_kernel(unsigned int* __restrict__ partial) {
    __shared__ unsigned int buf[2][2048];
    int t = threadIdx.x;  // 1024 threads
    buf[0][t]        = (t < NB_SCAN)        ? partial[t]        : 0u;
    buf[0][t + 1024] = (t + 1024 < NB_SCAN) ? partial[t + 1024] : 0u;
    __syncthreads();
    int src = 0;
    for (int off = 1; off < 2048; off <<= 1) {
        int dstb = 1 - src;
        for (int j = t; j < 2048; j += 1024) {
            unsigned int v = buf[src][j];
            if (j >= off) v += buf[src][j - off];
            buf[dstb][j] = v;
        }
        __syncthreads();
        src = 1 - src;
    }
    // exclusive
    if (t < NB_SCAN)        partial[t]        = (t == 0) ? 0u : buf[src][t - 1];
    if (t + 1024 < NB_SCAN) partial[t + 1024] = buf[src][t + 1023];
}

// ---------------- scan step 3: intra-block exclusive scan + offset -> rowptr, cursor ----------------
__global__ void scan3_kernel(const unsigned int* __restrict__ deg, const unsigned int* __restrict__ partial,
                             unsigned int* __restrict__ rowptr, unsigned int* __restrict__ cursor) {
    __shared__ unsigned int buf[2][256];
    int t = threadIdx.x;
    int i = blockIdx.x * 256 + t;
    unsigned int v = (i < N_NODES) ? deg[i] : 0u;
    buf[0][t] = v;
    __syncthreads();
    int src = 0;
    for (int off = 1; off < 256; off <<= 1) {
        int dstb = 1 - src;
        unsigned int x = buf[src][t];
        if (t >= off) x += buf[src][t - off];
        buf[dstb][t] = x;
        __syncthreads();
        src = 1 - src;
    }
    if (i < N_NODES) {
        unsigned int incl = buf[src][t];
        unsigned int excl = incl - v;          // exclusive within block
        unsigned int r = excl + partial[blockIdx.x];
        rowptr[i] = r;
        cursor[i] = r;
        if (i == N_NODES - 1) rowptr[N_NODES] = 2 * N_INTER;
    }
}

// ---------------- CSR fill: col[pos] = src node for each incoming edge of dst ----------------
__global__ void fill_kernel(const int* __restrict__ uid, const int* __restrict__ iid,
                            unsigned int* __restrict__ cursor, int* __restrict__ col) {
    int k = blockIdx.x * blockDim.x + threadIdx.x;
    if (k < N_INTER) {
        int u = uid[k];
        int it = N_USERS + iid[k];
        unsigned int pu = atomicAdd(&cursor[it], 1u);  // edge u -> it (incoming at it)
        col[pu] = u;
        unsigned int pi = atomicAdd(&cursor[u], 1u);   // edge it -> u (incoming at u)
        col[pi] = it;
    }
}

// ---------------- init emb_cur and acc(=d_out) ----------------
__global__ void init_kernel(const float4* __restrict__ ue, const float4* __restrict__ ie,
                            float4* __restrict__ cur, float4* __restrict__ acc) {
    int idx = blockIdx.x * blockDim.x + threadIdx.x;  // over N_NODES*16 float4s
    if (idx < N_NODES * 16) {
        float4 v = (idx < N_USERS * 16) ? ue[idx] : ie[idx - N_USERS * 16];
        cur[idx] = v;
        acc[idx] = v;
    }
}

// ---------------- gather SpMM: one wave per node, lane = dim ----------------
// nxt[n] = dinv[n] * sum_e dinv[col[e]] * cur[col[e]];  out = (out + nxt) * scale
__global__ void gather_kernel(const unsigned int* __restrict__ rowptr, const int* __restrict__ col,
                              const float* __restrict__ dinv,
                              const float* __restrict__ cur, float* __restrict__ nxt,
                              float* __restrict__ out, float scale, int write_nxt) {
    int wave = (blockIdx.x * blockDim.x + threadIdx.x) >> 6;  // node index
    int lane = threadIdx.x & 63;                              // dim
    if (wave >= N_NODES) return;
    int n = wave;
    unsigned int start = rowptr[n], end = rowptr[n + 1];
    float acc = 0.0f;
    for (unsigned int base = start; base < end; base += 64) {
        int cnt = (int)(end - base) < 64 ? (int)(end - base) : 64;
        int s = 0; float wj = 0.0f;
        if (lane < cnt) {
            s = col[base + lane];
            wj = dinv[s];
        }
        for (int j = 0; j < cnt; ++j) {
            int sj = __shfl(s, j);
            float w = __shfl(wj, j);
            acc += w * cur[(size_t)sj * DIM + lane];
        }
    }
    float r = dinv[n] * acc;
    size_t o = (size_t)n * DIM + lane;
    if (write_nxt) nxt[o] = r;
    out[o] = (out[o] + r) * scale;
}

extern "C" void kernel_launch(void* const* d_in, const int* in_sizes, int n_in,
                              void* d_out, int out_size, void* d_ws, size_t ws_size,
                              hipStream_t stream) {
    const float* ue = (const float*)d_in[0];
    const float* ie = (const float*)d_in[1];
    const int* uid = (const int*)d_in[2];
    const int* iid = (const int*)d_in[3];
    float* out = (float*)d_out;

    char* ws = (char*)d_ws;
    size_t off = 0;
    auto alloc = [&](size_t bytes) { char* p = ws + off; off = (off + bytes + 255) & ~(size_t)255; return p; };
    unsigned int* deg    = (unsigned int*)alloc((size_t)N_NODES * 4);
    float*        dinv   = (float*)alloc((size_t)N_NODES * 4);
    unsigned int* rowptr = (unsigned int*)alloc((size_t)(N_NODES + 1) * 4);
    unsigned int* cursor = (unsigned int*)alloc((size_t)N_NODES * 4);
    unsigned int* partial= (unsigned int*)alloc((size_t)2048 * 4);
    int*          col    = (int*)alloc((size_t)2 * N_INTER * 4);
    float*        buf0   = (float*)alloc((size_t)N_NODES * DIM * 4);
    float*        buf1   = (float*)alloc((size_t)N_NODES * DIM * 4);

    // --- CSR build ---
    hipMemsetAsync(deg, 0, (size_t)N_NODES * 4, stream);
    degree_kernel<<<(N_INTER + 255) / 256, 256, 0, stream>>>(uid, iid, deg);
    dinv_kernel<<<(N_NODES + 255) / 256, 256, 0, stream>>>(deg, dinv);
    scan1_kernel<<<NB_SCAN, 256, 0, stream>>>(deg, partial);
    scan2_kernel<<<1, 1024, 0, stream>>>(partial);
    scan3_kernel<<<NB_SCAN, 256, 0, stream>>>(deg, partial, rowptr, cursor);
    fill_kernel<<<(N_INTER + 255) / 256, 256, 0, stream>>>(uid, iid, cursor, col);

    // --- init ---
    init_kernel<<<(N_NODES * 16 + 255) / 256, 256, 0, stream>>>(
        (const float4*)ue, (const float4*)ie, (float4*)buf0, (float4*)out);

    // --- 3 propagation layers (gather, no atomics) ---
    float* cur = buf0;
    float* nxt = buf1;
    for (int l = 0; l < 3; ++l) {
        float scale = (l == 2) ? 0.25f : 1.0f;
        int write_nxt = (l < 2) ? 1 : 0;
        gather_kernel<<<(N_NODES * 64 + 255) / 256, 256, 0, stream>>>(
            rowptr, col, dinv, cur, nxt, out, scale, write_nxt);
        float* t = cur; cur = nxt; nxt = t;
    }
}

// Round 3
// 880.253 us; speedup vs baseline: 1.7912x; 1.0756x over previous
//
#include <hip/hip_runtime.h>

#define N_USERS 200000
#define N_ITEMS 100000
#define N_NODES 300000
#define DIM 64
#define N_INTER 1000000
#define NB_SCAN ((N_NODES + 255) / 256)   // 1172 blocks

typedef unsigned short bf16_t;

static __device__ __forceinline__ bf16_t f2bf(float f) {
    union { float f; unsigned int u; } v; v.f = f;
    unsigned int r = v.u + 0x7FFFu + ((v.u >> 16) & 1u);   // round-to-nearest-even
    return (bf16_t)(r >> 16);
}
static __device__ __forceinline__ float bf2f(bf16_t h) {
    union { unsigned int u; float f; } v; v.u = ((unsigned int)h) << 16;
    return v.f;
}

// ---------------- degree ----------------
__global__ void degree_kernel(const int* __restrict__ uid, const int* __restrict__ iid,
                              unsigned int* __restrict__ deg) {
    int k = blockIdx.x * blockDim.x + threadIdx.x;
    if (k < N_INTER) {
        atomicAdd(&deg[uid[k]], 1u);
        atomicAdd(&deg[N_USERS + iid[k]], 1u);
    }
}

// ---------------- d^{-1/2} ----------------
__global__ void dinv_kernel(const unsigned int* __restrict__ deg, float* __restrict__ dinv) {
    int n = blockIdx.x * blockDim.x + threadIdx.x;
    if (n < N_NODES) {
        unsigned int d = deg[n];
        dinv[n] = (d > 0) ? rsqrtf((float)d) : 0.0f;
    }
}

// ---------------- scan step 1: per-block sums ----------------
__global__ void scan1_kernel(const unsigned int* __restrict__ deg, unsigned int* __restrict__ partial) {
    __shared__ unsigned int sh[256];
    int t = threadIdx.x;
    int i = blockIdx.x * 256 + t;
    sh[t] = (i < N_NODES) ? deg[i] : 0u;
    __syncthreads();
    for (int o = 128; o > 0; o >>= 1) {
        if (t < o) sh[t] += sh[t + o];
        __syncthreads();
    }
    if (t == 0) partial[blockIdx.x] = sh[0];
}

// ---------------- scan step 2: exclusive scan of partials (single block) ----------------
__global__ void scan2_kernel(unsigned int* __restrict__ partial) {
    __shared__ unsigned int buf[2][2048];
    int t = threadIdx.x;  // 1024 threads
    buf[0][t]        = (t < NB_SCAN)        ? partial[t]        : 0u;
    buf[0][t + 1024] = (t + 1024 < NB_SCAN) ? partial[t + 1024] : 0u;
    __syncthreads();
    int src = 0;
    for (int off = 1; off < 2048; off <<= 1) {
        int dstb = 1 - src;
        for (int j = t; j < 2048; j += 1024) {
            unsigned int v = buf[src][j];
            if (j >= off) v += buf[src][j - off];
            buf[dstb][j] = v;
        }
        __syncthreads();
        src = 1 - src;
    }
    if (t < NB_SCAN)        partial[t]        = (t == 0) ? 0u : buf[src][t - 1];
    if (t + 1024 < NB_SCAN) partial[t + 1024] = buf[src][t + 1023];
}

// ---------------- scan step 3: intra-block exclusive scan + offset -> rowptr, cursor ----------------
__global__ void scan3_kernel(const unsigned int* __restrict__ deg, const unsigned int* __restrict__ partial,
                             unsigned int* __restrict__ rowptr, unsigned int* __restrict__ cursor) {
    __shared__ unsigned int buf[2][256];
    int t = threadIdx.x;
    int i = blockIdx.x * 256 + t;
    unsigned int v = (i < N_NODES) ? deg[i] : 0u;
    buf[0][t] = v;
    __syncthreads();
    int src = 0;
    for (int off = 1; off < 256; off <<= 1) {
        int dstb = 1 - src;
        unsigned int x = buf[src][t];
        if (t >= off) x += buf[src][t - off];
        buf[dstb][t] = x;
        __syncthreads();
        src = 1 - src;
    }
    if (i < N_NODES) {
        unsigned int incl = buf[src][t];
        unsigned int excl = incl - v;
        unsigned int r = excl + partial[blockIdx.x];
        rowptr[i] = r;
        cursor[i] = r;
        if (i == N_NODES - 1) rowptr[N_NODES] = 2 * N_INTER;
    }
}

// ---------------- CSR fill ----------------
__global__ void fill_kernel(const int* __restrict__ uid, const int* __restrict__ iid,
                            unsigned int* __restrict__ cursor, int* __restrict__ col) {
    int k = blockIdx.x * blockDim.x + threadIdx.x;
    if (k < N_INTER) {
        int u = uid[k];
        int it = N_USERS + iid[k];
        unsigned int pu = atomicAdd(&cursor[it], 1u);
        col[pu] = u;
        unsigned int pi = atomicAdd(&cursor[u], 1u);
        col[pi] = it;
    }
}

// ---------------- init: fp32 inputs -> bf16 layer-0 buffer ----------------
__global__ void init_kernel(const float4* __restrict__ ue, const float4* __restrict__ ie,
                            ushort4* __restrict__ cur) {
    int idx = blockIdx.x * blockDim.x + threadIdx.x;  // over N_NODES*16 float4s
    if (idx < N_NODES * 16) {
        float4 v = (idx < N_USERS * 16) ? ue[idx] : ie[idx - N_USERS * 16];
        ushort4 h;
        h.x = f2bf(v.x); h.y = f2bf(v.y); h.z = f2bf(v.z); h.w = f2bf(v.w);
        cur[idx] = h;
    }
}

// ---------------- gather SpMM (bf16 in / bf16 out): one wave per node, lane = dim --------
__global__ void gather_kernel(const unsigned int* __restrict__ rowptr, const int* __restrict__ col,
                              const float* __restrict__ dinv,
                              const bf16_t* __restrict__ cur, bf16_t* __restrict__ nxt) {
    int n = (blockIdx.x * blockDim.x + threadIdx.x) >> 6;  // node index
    int lane = threadIdx.x & 63;                           // dim
    if (n >= N_NODES) return;
    unsigned int start = rowptr[n], end = rowptr[n + 1];
    float acc = 0.0f;
    for (unsigned int base = start; base < end; base += 64) {
        int cnt = (int)(end - base) < 64 ? (int)(end - base) : 64;
        int s = 0; float wj = 0.0f;
        if (lane < cnt) {
            s = col[base + lane];
            wj = dinv[s];
        }
        for (int j = 0; j < cnt; ++j) {
            unsigned int sj = (unsigned int)__shfl(s, j);
            float w = __shfl(wj, j);
            acc += w * bf2f(cur[(sj << 6) + lane]);
        }
    }
    nxt[((unsigned int)n << 6) + lane] = f2bf(dinv[n] * acc);
}

// ---------------- final: out = (emb0 + l1 + l2 + l3) / 4 ----------------
__global__ void final_kernel(const float4* __restrict__ ue, const float4* __restrict__ ie,
                             const ushort4* __restrict__ b1, const ushort4* __restrict__ b2,
                             const ushort4* __restrict__ b3, float4* __restrict__ out) {
    int idx = blockIdx.x * blockDim.x + threadIdx.x;  // over N_NODES*16 quads
    if (idx < N_NODES * 16) {
        float4 v = (idx < N_USERS * 16) ? ue[idx] : ie[idx - N_USERS * 16];
        ushort4 h1 = b1[idx], h2 = b2[idx], h3 = b3[idx];
        float4 r;
        r.x = (v.x + bf2f(h1.x) + bf2f(h2.x) + bf2f(h3.x)) * 0.25f;
        r.y = (v.y + bf2f(h1.y) + bf2f(h2.y) + bf2f(h3.y)) * 0.25f;
        r.z = (v.z + bf2f(h1.z) + bf2f(h2.z) + bf2f(h3.z)) * 0.25f;
        r.w = (v.w + bf2f(h1.w) + bf2f(h2.w) + bf2f(h3.w)) * 0.25f;
        out[idx] = r;
    }
}

extern "C" void kernel_launch(void* const* d_in, const int* in_sizes, int n_in,
                              void* d_out, int out_size, void* d_ws, size_t ws_size,
                              hipStream_t stream) {
    const float* ue = (const float*)d_in[0];
    const float* ie = (const float*)d_in[1];
    const int* uid = (const int*)d_in[2];
    const int* iid = (const int*)d_in[3];
    float* out = (float*)d_out;

    char* ws = (char*)d_ws;
    size_t off = 0;
    auto alloc = [&](size_t bytes) { char* p = ws + off; off = (off + bytes + 255) & ~(size_t)255; return p; };
    unsigned int* deg    = (unsigned int*)alloc((size_t)N_NODES * 4);
    float*        dinv   = (float*)alloc((size_t)N_NODES * 4);
    unsigned int* rowptr = (unsigned int*)alloc((size_t)(N_NODES + 1) * 4);
    unsigned int* cursor = (unsigned int*)alloc((size_t)N_NODES * 4);
    unsigned int* partial= (unsigned int*)alloc((size_t)2048 * 4);
    int*          col    = (int*)alloc((size_t)2 * N_INTER * 4);
    bf16_t*       buf0   = (bf16_t*)alloc((size_t)N_NODES * DIM * 2);
    bf16_t*       buf1   = (bf16_t*)alloc((size_t)N_NODES * DIM * 2);
    bf16_t*       buf2   = (bf16_t*)alloc((size_t)N_NODES * DIM * 2);
    bf16_t*       buf3   = (bf16_t*)alloc((size_t)N_NODES * DIM * 2);

    // --- CSR build ---
    hipMemsetAsync(deg, 0, (size_t)N_NODES * 4, stream);
    degree_kernel<<<(N_INTER + 255) / 256, 256, 0, stream>>>(uid, iid, deg);
    dinv_kernel<<<(N_NODES + 255) / 256, 256, 0, stream>>>(deg, dinv);
    scan1_kernel<<<NB_SCAN, 256, 0, stream>>>(deg, partial);
    scan2_kernel<<<1, 1024, 0, stream>>>(partial);
    scan3_kernel<<<NB_SCAN, 256, 0, stream>>>(deg, partial, rowptr, cursor);
    fill_kernel<<<(N_INTER + 255) / 256, 256, 0, stream>>>(uid, iid, cursor, col);

    // --- init (fp32 -> bf16 layer 0) ---
    init_kernel<<<(N_NODES * 16 + 255) / 256, 256, 0, stream>>>(
        (const float4*)ue, (const float4*)ie, (ushort4*)buf0);

    // --- 3 propagation layers (gather, bf16) ---
    bf16_t* bufs[4] = {buf0, buf1, buf2, buf3};
    for (int l = 0; l < 3; ++l) {
        gather_kernel<<<(N_NODES * 64 + 255) / 256, 256, 0, stream>>>(
            rowptr, col, dinv, bufs[l], bufs[l + 1]);
    }

    // --- final sum ---
    final_kernel<<<(N_NODES * 16 + 255) / 256, 256, 0, stream>>>(
        (const float4*)ue, (const float4*)ie,
        (const ushort4*)buf1, (const ushort4*)buf2, (const ushort4*)buf3, (float4*)out);
}

// Round 4
// 817.073 us; speedup vs baseline: 1.9297x; 1.0773x over previous
//
#include <hip/hip_runtime.h>

#define N_USERS 200000
#define N_ITEMS 100000
#define N_NODES 300000
#define DIM 64
#define N_INTER 1000000

#define BSHIFT 9                       // 512 nodes per bucket
#define BNODES (1 << BSHIFT)
#define NBUCKET ((N_NODES + BNODES - 1) >> BSHIFT)   // 586
#define NSLOT 8                        // XCD-ish sub-buckets
#define CAP 1024                       // entries per (bucket, slot); avg ~640 max, +15 sigma safe

typedef unsigned short bf16_t;
typedef unsigned int u32;

static __device__ __forceinline__ bf16_t f2bf(float f) {
    union { float f; u32 u; } v; v.f = f;
    u32 r = v.u + 0x7FFFu + ((v.u >> 16) & 1u);
    return (bf16_t)(r >> 16);
}
static __device__ __forceinline__ float bf2f(bf16_t h) {
    union { u32 u; float f; } v; v.u = ((u32)h) << 16;
    return v.f;
}

// ---------------- phase 1: bucket scatter of (local_dst, src) packed u32 ----------------
// entry = (local_dst << 19) | src   (src < 300000 < 2^19, local_dst < 512)
__global__ void phase1_kernel(const int* __restrict__ uid, const int* __restrict__ iid,
                              u32* __restrict__ cursor, u32* __restrict__ bdata) {
    int k = blockIdx.x * blockDim.x + threadIdx.x;
    if (k >= N_INTER) return;
    int slot = blockIdx.x & (NSLOT - 1);   // round-robin block->XCD => L2-local appends
    int u = uid[k];
    int it = N_USERS + iid[k];
    {   // edge u -> it (incoming at it)
        int b = it >> BSHIFT;
        u32 c = (u32)(b * NSLOT + slot);
        u32 pos = atomicAdd(&cursor[c], 1u);
        if (pos < CAP) bdata[c * CAP + pos] = (((u32)(it - (b << BSHIFT))) << 19) | (u32)u;
    }
    {   // edge it -> u (incoming at u)
        int b = u >> BSHIFT;
        u32 c = (u32)(b * NSLOT + slot);
        u32 pos = atomicAdd(&cursor[c], 1u);
        if (pos < CAP) bdata[c * CAP + pos] = (((u32)(u - (b << BSHIFT))) << 19) | (u32)it;
    }
}

// ---------------- bucket scan: exclusive prefix of bucket totals ----------------
__global__ void bucket_scan_kernel(const u32* __restrict__ cursor, u32* __restrict__ bstart,
                                   u32* __restrict__ rowptr) {
    __shared__ u32 buf[2][1024];
    int t = threadIdx.x;  // 1024 threads
    u32 tot = 0;
    if (t < NBUCKET) {
        for (int x = 0; x < NSLOT; ++x) {
            u32 c = cursor[t * NSLOT + x];
            tot += (c < CAP) ? c : CAP;
        }
    }
    buf[0][t] = tot;
    __syncthreads();
    int s = 0;
    for (int off = 1; off < 1024; off <<= 1) {
        u32 v = buf[s][t];
        if (t >= off) v += buf[s][t - off];
        buf[1 - s][t] = v;
        __syncthreads();
        s = 1 - s;
    }
    if (t < NBUCKET) bstart[t] = buf[s][t] - tot;   // exclusive
    if (t == 0) rowptr[N_NODES] = 2 * N_INTER;
}

// ---------------- phase 2: per-bucket CSR build (one block per bucket) ----------------
__global__ void phase2_kernel(const u32* __restrict__ cursor, const u32* __restrict__ bdata,
                              const u32* __restrict__ bstart,
                              u32* __restrict__ rowptr, float* __restrict__ dinv,
                              int* __restrict__ col) {
    __shared__ u32 cnt[BNODES];       // per-node incoming count
    __shared__ u32 sbuf[2][BNODES];   // scan buffers
    __shared__ u32 curL[BNODES];      // local cursors
    __shared__ u32 m8[NSLOT];

    int b = blockIdx.x;
    int t = threadIdx.x;              // 256 threads
    int base = b << BSHIFT;
    u32 bs = bstart[b];

    if (t < NSLOT) {
        u32 c = cursor[b * NSLOT + t];
        m8[t] = (c < CAP) ? c : CAP;
    }
    cnt[t] = 0; cnt[t + 256] = 0;
    __syncthreads();

    // pass A: count per node
    for (int x = 0; x < NSLOT; ++x) {
        const u32* src = bdata + (u32)(b * NSLOT + x) * CAP;
        u32 m = m8[x];
        for (u32 e = t; e < m; e += 256) {
            u32 v = src[e];
            atomicAdd(&cnt[v >> 19], 1u);
        }
    }
    __syncthreads();

    // inclusive scan of 512 counts (Hillis-Steele, 2 elems/thread)
    sbuf[0][t] = cnt[t]; sbuf[0][t + 256] = cnt[t + 256];
    __syncthreads();
    int s = 0;
    for (int off = 1; off < BNODES; off <<= 1) {
        #pragma unroll
        for (int j = 0; j < 2; ++j) {
            int idx = t + j * 256;
            u32 v = sbuf[s][idx];
            if (idx >= off) v += sbuf[s][idx - off];
            sbuf[1 - s][idx] = v;
        }
        __syncthreads();
        s = 1 - s;
    }

    // rowptr, dinv, local cursors (exclusive = incl - cnt)
    #pragma unroll
    for (int j = 0; j < 2; ++j) {
        int i = t + j * 256;
        int node = base + i;
        u32 c = cnt[i];
        u32 excl = sbuf[s][i] - c;
        curL[i] = excl;
        if (node < N_NODES) {
            rowptr[node] = bs + excl;
            dinv[node] = (c > 0) ? rsqrtf((float)c) : 0.0f;
        }
    }
    __syncthreads();

    // pass B: place col entries (contiguous region [bs, bs+total))
    for (int x = 0; x < NSLOT; ++x) {
        const u32* src = bdata + (u32)(b * NSLOT + x) * CAP;
        u32 m = m8[x];
        for (u32 e = t; e < m; e += 256) {
            u32 v = src[e];
            u32 ln = v >> 19;
            u32 pos = atomicAdd(&curL[ln], 1u);
            col[bs + pos] = (int)(v & 0x7FFFFu);
        }
    }
}

// ---------------- init: fp32 inputs -> bf16 layer-0 buffer ----------------
__global__ void init_kernel(const float4* __restrict__ ue, const float4* __restrict__ ie,
                            ushort4* __restrict__ cur) {
    int idx = blockIdx.x * blockDim.x + threadIdx.x;
    if (idx < N_NODES * 16) {
        float4 v = (idx < N_USERS * 16) ? ue[idx] : ie[idx - N_USERS * 16];
        ushort4 h;
        h.x = f2bf(v.x); h.y = f2bf(v.y); h.z = f2bf(v.z); h.w = f2bf(v.w);
        cur[idx] = h;
    }
}

// ---------------- gather SpMM (bf16 -> bf16): one wave per node, lane = dim ----------------
__global__ void gather_kernel(const u32* __restrict__ rowptr, const int* __restrict__ col,
                              const float* __restrict__ dinv,
                              const bf16_t* __restrict__ cur, bf16_t* __restrict__ nxt) {
    int n = (blockIdx.x * blockDim.x + threadIdx.x) >> 6;
    int lane = threadIdx.x & 63;
    if (n >= N_NODES) return;
    u32 start = rowptr[n], end = rowptr[n + 1];
    float acc = 0.0f;
    for (u32 base = start; base < end; base += 64) {
        int cnt = (int)(end - base) < 64 ? (int)(end - base) : 64;
        int s = 0; float wj = 0.0f;
        if (lane < cnt) {
            s = col[base + lane];
            wj = dinv[s];
        }
        for (int j = 0; j < cnt; ++j) {
            u32 sj = (u32)__shfl(s, j);
            float w = __shfl(wj, j);
            acc += w * bf2f(cur[(sj << 6) + lane]);
        }
    }
    nxt[((u32)n << 6) + lane] = f2bf(dinv[n] * acc);
}

// ---------------- layer-3 gather fused with final combine ----------------
// out[n] = (emb0[n] + b1[n] + b2[n] + dinv[n]*gather(b2)) * 0.25   (fp32 out)
__global__ void gather_final_kernel(const u32* __restrict__ rowptr, const int* __restrict__ col,
                                    const float* __restrict__ dinv,
                                    const bf16_t* __restrict__ b1, const bf16_t* __restrict__ b2,
                                    const float* __restrict__ ue, const float* __restrict__ ie,
                                    float* __restrict__ out) {
    int n = (blockIdx.x * blockDim.x + threadIdx.x) >> 6;
    int lane = threadIdx.x & 63;
    if (n >= N_NODES) return;
    u32 start = rowptr[n], end = rowptr[n + 1];
    float acc = 0.0f;
    for (u32 base = start; base < end; base += 64) {
        int cnt = (int)(end - base) < 64 ? (int)(end - base) : 64;
        int s = 0; float wj = 0.0f;
        if (lane < cnt) {
            s = col[base + lane];
            wj = dinv[s];
        }
        for (int j = 0; j < cnt; ++j) {
            u32 sj = (u32)__shfl(s, j);
            float w = __shfl(wj, j);
            acc += w * bf2f(b2[(sj << 6) + lane]);
        }
    }
    float r = dinv[n] * acc;
    u32 o = ((u32)n << 6) + lane;
    float e0 = (n < N_USERS) ? ue[o] : ie[o - (u32)N_USERS * DIM];
    out[o] = (e0 + bf2f(b1[o]) + bf2f(b2[o]) + r) * 0.25f;
}

extern "C" void kernel_launch(void* const* d_in, const int* in_sizes, int n_in,
                              void* d_out, int out_size, void* d_ws, size_t ws_size,
                              hipStream_t stream) {
    const float* ue = (const float*)d_in[0];
    const float* ie = (const float*)d_in[1];
    const int* uid = (const int*)d_in[2];
    const int* iid = (const int*)d_in[3];
    float* out = (float*)d_out;

    char* ws = (char*)d_ws;
    size_t off = 0;
    auto alloc = [&](size_t bytes) { char* p = ws + off; off = (off + bytes + 255) & ~(size_t)255; return p; };
    u32*    cursor = (u32*)alloc((size_t)NBUCKET * NSLOT * 4);
    u32*    bstart = (u32*)alloc((size_t)(NBUCKET + 1) * 4);
    u32*    rowptr = (u32*)alloc((size_t)(N_NODES + 1) * 4);
    float*  dinv   = (float*)alloc((size_t)N_NODES * 4);
    int*    col    = (int*)alloc((size_t)2 * N_INTER * 4);
    u32*    bdata  = (u32*)alloc((size_t)NBUCKET * NSLOT * CAP * 4);   // 19.2 MB
    bf16_t* buf0   = (bf16_t*)alloc((size_t)N_NODES * DIM * 2);
    bf16_t* buf1   = (bf16_t*)alloc((size_t)N_NODES * DIM * 2);
    bf16_t* buf2   = (bf16_t*)alloc((size_t)N_NODES * DIM * 2);

    // --- CSR build (bucketed, no global scans, no separate degree pass) ---
    hipMemsetAsync(cursor, 0, (size_t)NBUCKET * NSLOT * 4, stream);
    phase1_kernel<<<(N_INTER + 255) / 256, 256, 0, stream>>>(uid, iid, cursor, bdata);
    bucket_scan_kernel<<<1, 1024, 0, stream>>>(cursor, bstart, rowptr);
    phase2_kernel<<<NBUCKET, 256, 0, stream>>>(cursor, bdata, bstart, rowptr, dinv, col);

    // --- init (fp32 -> bf16 layer 0) ---
    init_kernel<<<(N_NODES * 16 + 255) / 256, 256, 0, stream>>>(
        (const float4*)ue, (const float4*)ie, (ushort4*)buf0);

    // --- layers 1,2 (gather), layer 3 fused with final combine ---
    gather_kernel<<<(N_NODES * 64 + 255) / 256, 256, 0, stream>>>(rowptr, col, dinv, buf0, buf1);
    gather_kernel<<<(N_NODES * 64 + 255) / 256, 256, 0, stream>>>(rowptr, col, dinv, buf1, buf2);
    gather_final_kernel<<<(N_NODES * 64 + 255) / 256, 256, 0, stream>>>(
        rowptr, col, dinv, buf1, buf2, ue, ie, out);
}

// Round 5
// 535.294 us; speedup vs baseline: 2.9455x; 1.5264x over previous
//
#include <hip/hip_runtime.h>

#define N_USERS 200000
#define N_ITEMS 100000
#define N_NODES 300000
#define DIM 64
#define N_INTER 1000000

#define BSHIFT 10                      // 1024 nodes per bucket
#define BNODES (1 << BSHIFT)
#define NBUCKET ((N_NODES + BNODES - 1) >> BSHIFT)   // 293
#define TILE 4096                      // interactions per block in hist/place
#define NBLK_P ((N_INTER + TILE - 1) / TILE)          // 245

typedef unsigned short bf16_t;
typedef unsigned int u32;

static __device__ __forceinline__ bf16_t f2bf(float f) {
    union { float f; u32 u; } v; v.f = f;
    u32 r = v.u + 0x7FFFu + ((v.u >> 16) & 1u);
    return (bf16_t)(r >> 16);
}
static __device__ __forceinline__ float bf2f(bf16_t h) {
    union { u32 u; float f; } v; v.u = ((u32)h) << 16;
    return v.f;
}

// ---------------- 1. bucket histogram (LDS, then one merge per bucket) ----------------
__global__ void hist_kernel(const int* __restrict__ uid, const int* __restrict__ iid,
                            u32* __restrict__ bucket_count) {
    __shared__ u32 h[NBUCKET];
    int t = threadIdx.x;
    for (int i = t; i < NBUCKET; i += 256) h[i] = 0;
    __syncthreads();
    int base = blockIdx.x * TILE;
    int end = base + TILE; if (end > N_INTER) end = N_INTER;
    for (int k = base + t; k < end; k += 256) {
        int u = uid[k];
        int it = N_USERS + iid[k];
        atomicAdd(&h[it >> BSHIFT], 1u);   // edge u->it lands in it's bucket
        atomicAdd(&h[u >> BSHIFT], 1u);    // edge it->u lands in u's bucket
    }
    __syncthreads();
    for (int i = t; i < NBUCKET; i += 256)
        if (h[i]) atomicAdd(&bucket_count[i], h[i]);
}

// ---------------- 2. scan bucket counts -> bstart, init cursors ----------------
__global__ void scan_kernel(const u32* __restrict__ bucket_count, u32* __restrict__ bstart,
                            u32* __restrict__ bucket_cursor, u32* __restrict__ rowptr) {
    __shared__ u32 buf[2][512];
    int t = threadIdx.x;  // 512 threads
    u32 v0 = (t < NBUCKET) ? bucket_count[t] : 0u;
    buf[0][t] = v0;
    __syncthreads();
    int s = 0;
    for (int off = 1; off < 512; off <<= 1) {
        u32 v = buf[s][t];
        if (t >= off) v += buf[s][t - off];
        buf[1 - s][t] = v;
        __syncthreads();
        s = 1 - s;
    }
    if (t < NBUCKET) {
        u32 excl = buf[s][t] - v0;
        bstart[t] = excl;
        bucket_cursor[t] = excl;
    }
    if (t == 0) {
        bstart[NBUCKET] = 2 * N_INTER;
        rowptr[N_NODES] = 2 * N_INTER;
    }
}

// ---------------- 3. place: exact per-(block,bucket) reservations ----------------
// entry = (local_dst << 19) | src   (src < 2^19, local_dst < 1024 -> bits 19..28)
__global__ void place_kernel(const int* __restrict__ uid, const int* __restrict__ iid,
                             u32* __restrict__ bucket_cursor, u32* __restrict__ bdata) {
    __shared__ u32 h[NBUCKET];      // pass1: counts; pass2: local cursor
    __shared__ u32 basesh[NBUCKET]; // reserved global base per bucket
    int t = threadIdx.x;
    for (int i = t; i < NBUCKET; i += 256) h[i] = 0;
    __syncthreads();
    int base = blockIdx.x * TILE;
    int end = base + TILE; if (end > N_INTER) end = N_INTER;
    // pass 1: local histogram
    for (int k = base + t; k < end; k += 256) {
        int u = uid[k];
        int it = N_USERS + iid[k];
        atomicAdd(&h[it >> BSHIFT], 1u);
        atomicAdd(&h[u >> BSHIFT], 1u);
    }
    __syncthreads();
    // reserve ranges
    for (int i = t; i < NBUCKET; i += 256) {
        u32 c = h[i];
        basesh[i] = c ? atomicAdd(&bucket_cursor[i], c) : 0u;
        h[i] = 0;
    }
    __syncthreads();
    // pass 2: place
    for (int k = base + t; k < end; k += 256) {
        int u = uid[k];
        int it = N_USERS + iid[k];
        {
            int b = it >> BSHIFT;
            u32 pos = basesh[b] + atomicAdd(&h[b], 1u);
            bdata[pos] = (((u32)(it & (BNODES - 1))) << 19) | (u32)u;
        }
        {
            int b = u >> BSHIFT;
            u32 pos = basesh[b] + atomicAdd(&h[b], 1u);
            bdata[pos] = (((u32)(u & (BNODES - 1))) << 19) | (u32)it;
        }
    }
}

// ---------------- 4. per-bucket CSR finalize: rowptr, dinv, col ----------------
__global__ void csr_kernel(const u32* __restrict__ bstart, const u32* __restrict__ bdata,
                           u32* __restrict__ rowptr, float* __restrict__ dinv,
                           int* __restrict__ col) {
    __shared__ u32 cnt[BNODES];
    __shared__ u32 sb[2][BNODES];
    __shared__ u32 cur[BNODES];
    int b = blockIdx.x;
    int t = threadIdx.x;               // 256 threads
    int nbase = b << BSHIFT;
    u32 bs = bstart[b], be = bstart[b + 1];
    u32 m = be - bs;

    #pragma unroll
    for (int j = 0; j < 4; ++j) cnt[t + j * 256] = 0;
    __syncthreads();
    // pass A: count per local node
    for (u32 e = t; e < m; e += 256) {
        u32 v = bdata[bs + e];
        atomicAdd(&cnt[v >> 19], 1u);
    }
    __syncthreads();
    // inclusive scan of 1024 (Hillis-Steele, 4 elems/thread)
    #pragma unroll
    for (int j = 0; j < 4; ++j) sb[0][t + j * 256] = cnt[t + j * 256];
    __syncthreads();
    int s = 0;
    for (int off = 1; off < BNODES; off <<= 1) {
        #pragma unroll
        for (int j = 0; j < 4; ++j) {
            int idx = t + j * 256;
            u32 v = sb[s][idx];
            if (idx >= off) v += sb[s][idx - off];
            sb[1 - s][idx] = v;
        }
        __syncthreads();
        s = 1 - s;
    }
    // rowptr, dinv, cursors
    #pragma unroll
    for (int j = 0; j < 4; ++j) {
        int idx = t + j * 256;
        int node = nbase + idx;
        u32 c = cnt[idx];
        u32 excl = sb[s][idx] - c;
        cur[idx] = excl;
        if (node < N_NODES) {
            rowptr[node] = bs + excl;
            dinv[node] = (c > 0) ? rsqrtf((float)c) : 0.0f;
        }
    }
    __syncthreads();
    // pass B: place col entries into contiguous [bs, be)
    for (u32 e = t; e < m; e += 256) {
        u32 v = bdata[bs + e];
        u32 ln = v >> 19;
        u32 pos = atomicAdd(&cur[ln], 1u);
        col[bs + pos] = (int)(v & 0x7FFFFu);
    }
}

// ---------------- 5. edge records: (src, dinv[src]) ----------------
__global__ void ecol_kernel(const int* __restrict__ col, const float* __restrict__ dinv,
                            int2* __restrict__ ecol) {
    int e = blockIdx.x * blockDim.x + threadIdx.x;
    if (e < 2 * N_INTER) {
        int s = col[e];
        ecol[e] = make_int2(s, __float_as_int(dinv[s]));
    }
}

// ---------------- init: fp32 inputs -> bf16 layer-0 buffer ----------------
__global__ void init_kernel(const float4* __restrict__ ue, const float4* __restrict__ ie,
                            ushort4* __restrict__ cur) {
    int idx = blockIdx.x * blockDim.x + threadIdx.x;
    if (idx < N_NODES * 16) {
        float4 v = (idx < N_USERS * 16) ? ue[idx] : ie[idx - N_USERS * 16];
        ushort4 h;
        h.x = f2bf(v.x); h.y = f2bf(v.y); h.z = f2bf(v.z); h.w = f2bf(v.w);
        cur[idx] = h;
    }
}

// ---------------- gather SpMM: one wave per node, 4-way batched inner loop ----------------
__global__ void gather_kernel(const u32* __restrict__ rowptr, const int2* __restrict__ ecol,
                              const float* __restrict__ dinv,
                              const bf16_t* __restrict__ cur, bf16_t* __restrict__ nxt) {
    int n = (blockIdx.x * blockDim.x + threadIdx.x) >> 6;
    int lane = threadIdx.x & 63;
    if (n >= N_NODES) return;
    u32 start = rowptr[n], end = rowptr[n + 1];
    float acc = 0.0f;
    for (u32 base = start; base < end; base += 64) {
        int cnt = (int)(end - base) < 64 ? (int)(end - base) : 64;
        int2 e = make_int2(0, 0);
        if (lane < cnt) e = ecol[base + lane];
        int s = e.x; float w = __int_as_float(e.y);
        int j = 0;
        for (; j + 4 <= cnt; j += 4) {
            int s0 = __shfl(s, j), s1 = __shfl(s, j + 1), s2 = __shfl(s, j + 2), s3 = __shfl(s, j + 3);
            float w0 = __shfl(w, j), w1 = __shfl(w, j + 1), w2 = __shfl(w, j + 2), w3 = __shfl(w, j + 3);
            float r0 = bf2f(cur[((u32)s0 << 6) + lane]);
            float r1 = bf2f(cur[((u32)s1 << 6) + lane]);
            float r2 = bf2f(cur[((u32)s2 << 6) + lane]);
            float r3 = bf2f(cur[((u32)s3 << 6) + lane]);
            acc += w0 * r0; acc += w1 * r1; acc += w2 * r2; acc += w3 * r3;
        }
        for (; j < cnt; ++j) {
            int sj = __shfl(s, j);
            float wj = __shfl(w, j);
            acc += wj * bf2f(cur[((u32)sj << 6) + lane]);
        }
    }
    nxt[((u32)n << 6) + lane] = f2bf(dinv[n] * acc);
}

// ---------------- layer-3 gather fused with final combine ----------------
__global__ void gather_final_kernel(const u32* __restrict__ rowptr, const int2* __restrict__ ecol,
                                    const float* __restrict__ dinv,
                                    const bf16_t* __restrict__ b1, const bf16_t* __restrict__ b2,
                                    const float* __restrict__ ue, const float* __restrict__ ie,
                                    float* __restrict__ out) {
    int n = (blockIdx.x * blockDim.x + threadIdx.x) >> 6;
    int lane = threadIdx.x & 63;
    if (n >= N_NODES) return;
    u32 start = rowptr[n], end = rowptr[n + 1];
    float acc = 0.0f;
    for (u32 base = start; base < end; base += 64) {
        int cnt = (int)(end - base) < 64 ? (int)(end - base) : 64;
        int2 e = make_int2(0, 0);
        if (lane < cnt) e = ecol[base + lane];
        int s = e.x; float w = __int_as_float(e.y);
        int j = 0;
        for (; j + 4 <= cnt; j += 4) {
            int s0 = __shfl(s, j), s1 = __shfl(s, j + 1), s2 = __shfl(s, j + 2), s3 = __shfl(s, j + 3);
            float w0 = __shfl(w, j), w1 = __shfl(w, j + 1), w2 = __shfl(w, j + 2), w3 = __shfl(w, j + 3);
            float r0 = bf2f(b2[((u32)s0 << 6) + lane]);
            float r1 = bf2f(b2[((u32)s1 << 6) + lane]);
            float r2 = bf2f(b2[((u32)s2 << 6) + lane]);
            float r3 = bf2f(b2[((u32)s3 << 6) + lane]);
            acc += w0 * r0; acc += w1 * r1; acc += w2 * r2; acc += w3 * r3;
        }
        for (; j < cnt; ++j) {
            int sj = __shfl(s, j);
            float wj = __shfl(w, j);
            acc += wj * bf2f(b2[((u32)sj << 6) + lane]);
        }
    }
    float r = dinv[n] * acc;
    u32 o = ((u32)n << 6) + lane;
    float e0 = (n < N_USERS) ? ue[o] : ie[o - (u32)N_USERS * DIM];
    out[o] = (e0 + bf2f(b1[o]) + bf2f(b2[o]) + r) * 0.25f;
}

extern "C" void kernel_launch(void* const* d_in, const int* in_sizes, int n_in,
                              void* d_out, int out_size, void* d_ws, size_t ws_size,
                              hipStream_t stream) {
    const float* ue = (const float*)d_in[0];
    const float* ie = (const float*)d_in[1];
    const int* uid = (const int*)d_in[2];
    const int* iid = (const int*)d_in[3];
    float* out = (float*)d_out;

    char* ws = (char*)d_ws;
    size_t off = 0;
    auto alloc = [&](size_t bytes) { char* p = ws + off; off = (off + bytes + 255) & ~(size_t)255; return p; };
    u32*    bucket_count  = (u32*)alloc((size_t)NBUCKET * 4);
    u32*    bstart        = (u32*)alloc((size_t)(NBUCKET + 1) * 4);
    u32*    bucket_cursor = (u32*)alloc((size_t)NBUCKET * 4);
    u32*    rowptr        = (u32*)alloc((size_t)(N_NODES + 1) * 4);
    float*  dinv          = (float*)alloc((size_t)N_NODES * 4);
    u32*    bdata         = (u32*)alloc((size_t)2 * N_INTER * 4);     // 8 MB
    int*    col           = (int*)alloc((size_t)2 * N_INTER * 4);     // 8 MB
    int2*   ecol          = (int2*)alloc((size_t)2 * N_INTER * 8);    // 16 MB
    bf16_t* buf0          = (bf16_t*)alloc((size_t)N_NODES * DIM * 2);
    bf16_t* buf1          = (bf16_t*)alloc((size_t)N_NODES * DIM * 2);
    bf16_t* buf2          = (bf16_t*)alloc((size_t)N_NODES * DIM * 2);

    // --- CSR build: exact-reservation bucketed, line-friendly writes throughout ---
    hipMemsetAsync(bucket_count, 0, (size_t)NBUCKET * 4, stream);
    hist_kernel<<<NBLK_P, 256, 0, stream>>>(uid, iid, bucket_count);
    scan_kernel<<<1, 512, 0, stream>>>(bucket_count, bstart, bucket_cursor, rowptr);
    place_kernel<<<NBLK_P, 256, 0, stream>>>(uid, iid, bucket_cursor, bdata);
    csr_kernel<<<NBUCKET, 256, 0, stream>>>(bstart, bdata, rowptr, dinv, col);
    ecol_kernel<<<(2 * N_INTER + 255) / 256, 256, 0, stream>>>(col, dinv, ecol);

    // --- init (fp32 -> bf16 layer 0) ---
    init_kernel<<<(N_NODES * 16 + 255) / 256, 256, 0, stream>>>(
        (const float4*)ue, (const float4*)ie, (ushort4*)buf0);

    // --- layers 1,2 gather; layer 3 fused with final combine ---
    gather_kernel<<<(N_NODES * 64 + 255) / 256, 256, 0, stream>>>(rowptr, ecol, dinv, buf0, buf1);
    gather_kernel<<<(N_NODES * 64 + 255) / 256, 256, 0, stream>>>(rowptr, ecol, dinv, buf1, buf2);
    gather_final_kernel<<<(N_NODES * 64 + 255) / 256, 256, 0, stream>>>(
        rowptr, ecol, dinv, buf1, buf2, ue, ie, out);
}